// Round 12
// baseline (349.678 us; speedup 1.0000x reference)
//
#include <hip/hip_runtime.h>
#include <hip/hip_bf16.h>

#define L_SEQ 2048
#define D_HEAD 64
#define NHEADS 64   // B*H
#define QSCALE (0.125f * 1.44269504088896340736f)  // 1/sqrt(64) * log2(e)

typedef __attribute__((ext_vector_type(8))) __bf16 bf16x8;
typedef __attribute__((ext_vector_type(16))) float f32x16;

// [rows][64] bf16 tile (128B rows), XOR-swizzled (G4).
__device__ __forceinline__ int swz(int row, int col) {
    int off = (row << 7) | (col << 1);
    return off ^ ((row & 7) << 4);
}
__device__ __forceinline__ bf16x8 read_frag(const char* lds, int row, int col) {
    return *reinterpret_cast<const bf16x8*>(lds + swz(row, col));
}
__device__ __forceinline__ void pack_write(char* lds, int row, int c4, float4 v,
                                           float4 sc) {
    union { __bf16 h[4]; unsigned long long u; } pk;
    pk.h[0] = (__bf16)(v.x * sc.x);
    pk.h[1] = (__bf16)(v.y * sc.y);
    pk.h[2] = (__bf16)(v.z * sc.z);
    pk.h[3] = (__bf16)(v.w * sc.w);
    *reinterpret_cast<unsigned long long*>(lds + swz(row, c4)) = pk.u;
}

__device__ __forceinline__ unsigned cvt_pk_bf16(float lo, float hi) {
    unsigned r;
    asm("v_cvt_pk_bf16_f32 %0, %1, %2" : "=v"(r) : "v"(lo), "v"(hi));
    return r;
}

// -------- Pass 1: invl[bh][q] = 1 / sum_k exp2(QSCALE*(Q.K)) ----------------
// Round-8/10 version (measured ~40-48 us): q-tile 128, 4 waves = wq2 x wk2,
// k-step 64 double-buffered, one barrier/step. Grid 1024 @ 4/CU = clean.
__global__ __launch_bounds__(256, 4) void attn_pass1(const float* __restrict__ Q,
                                                     const float* __restrict__ K,
                                                     float* __restrict__ invl) {
    __shared__ __align__(16) char lds[16384];   // Q stage, then 2 x 8KB K dbuf
    __shared__ float red[2][128];

    int bid = blockIdx.x;
    int sb = (bid & 7) * 128 + (bid >> 3);   // bijective XCD swizzle (1024 = 8*128)
    int bh = sb >> 4;
    int q0 = (sb & 15) << 7;
    const float* Qh = Q + (size_t)bh * L_SEQ * D_HEAD + (size_t)q0 * D_HEAD;
    const float* Kh = K + (size_t)bh * L_SEQ * D_HEAD;

    int t = threadIdx.x, lane = t & 63, w = t >> 6;
    int wq = w >> 1, wk = w & 1;
    int hl = lane >> 5, l31 = lane & 31;
    int r0 = t >> 4;          // 0..15
    int c4 = (t & 15) << 2;

    // stage Q[128][64] (rows 0..127 across the 16KB region)
    {
        float4 qs = make_float4(QSCALE, QSCALE, QSCALE, QSCALE);
#pragma unroll
        for (int i = 0; i < 8; ++i) {
            float4 v = *reinterpret_cast<const float4*>(Qh + (size_t)(r0 + i * 16) * D_HEAD + c4);
            pack_write(lds, r0 + i * 16, c4, v, qs);
        }
    }
    __syncthreads();
    bf16x8 qfrag[2][4];
#pragma unroll
    for (int qb = 0; qb < 2; ++qb)
#pragma unroll
        for (int m = 0; m < 4; ++m)
            qfrag[qb][m] = read_frag(lds, wq * 64 + qb * 32 + l31, m * 16 + hl * 8);
    __syncthreads();
    // stage K tile 0 into buf0
    {
        float4 one = make_float4(1.f, 1.f, 1.f, 1.f);
#pragma unroll
        for (int i = 0; i < 4; ++i) {
            float4 v = *reinterpret_cast<const float4*>(Kh + (size_t)(r0 + i * 16) * D_HEAD + c4);
            pack_write(lds, r0 + i * 16, c4, v, one);
        }
    }
    __syncthreads();

    float lsum[2][16];
#pragma unroll
    for (int qb = 0; qb < 2; ++qb)
#pragma unroll
        for (int r = 0; r < 16; ++r) lsum[qb][r] = 0.f;

    for (int k0 = 0; k0 < L_SEQ; k0 += 64) {
        int c = (k0 >> 6) & 1;
        const char* kcur = lds + (c ? 8192 : 0);
        char* knext = lds + (c ? 0 : 8192);

        int nk0 = (k0 + 64) & (L_SEQ - 1);
        float4 kreg[4];
#pragma unroll
        for (int i = 0; i < 4; ++i)
            kreg[i] = *reinterpret_cast<const float4*>(Kh + (size_t)(nk0 + r0 + i * 16) * D_HEAD + c4);

        bf16x8 kfr[4];
#pragma unroll
        for (int m = 0; m < 4; ++m)
            kfr[m] = read_frag(kcur, wk * 32 + l31, m * 16 + hl * 8);

        __builtin_amdgcn_s_setprio(1);
#pragma unroll
        for (int qb = 0; qb < 2; ++qb) {
            f32x16 s;
#pragma unroll
            for (int r = 0; r < 16; ++r) s[r] = 0.f;
#pragma unroll
            for (int m = 0; m < 4; ++m)
                s = __builtin_amdgcn_mfma_f32_32x32x16_bf16(qfrag[qb][m], kfr[m], s, 0, 0, 0);
#pragma unroll
            for (int r = 0; r < 16; ++r)
                lsum[qb][r] += __builtin_amdgcn_exp2f(s[r]);
        }
        __builtin_amdgcn_s_setprio(0);

        {
            float4 one = make_float4(1.f, 1.f, 1.f, 1.f);
#pragma unroll
            for (int i = 0; i < 4; ++i)
                pack_write(knext, r0 + i * 16, c4, kreg[i], one);
        }
        __syncthreads();   // single barrier per step (double-buffered)
    }

    // reduce over this wave's 32 k-lanes
#pragma unroll
    for (int qb = 0; qb < 2; ++qb)
#pragma unroll
        for (int r = 0; r < 16; ++r) {
            float v = lsum[qb][r];
            v += __shfl_xor(v, 1);
            v += __shfl_xor(v, 2);
            v += __shfl_xor(v, 4);
            v += __shfl_xor(v, 8);
            v += __shfl_xor(v, 16);
            lsum[qb][r] = v;
        }
    if (l31 == 0) {
#pragma unroll
        for (int qb = 0; qb < 2; ++qb)
#pragma unroll
            for (int r = 0; r < 16; ++r)
                red[wk][wq * 64 + qb * 32 + (r & 3) + 8 * (r >> 2) + 4 * hl] = lsum[qb][r];
    }
    __syncthreads();
    if (t < 128) {
        float ssum = red[0][t] + red[1][t];
        invl[(size_t)bh * L_SEQ + q0 + t] = 1.0f / ssum;
    }
}

// -------- Pass 2: Out[d, k-tile] = sum_q (V[d,q]*invl[q]) * exp2(s[q,k]) ----
// r6/r7 structure (1:2 read:MFMA) at FULL occupancy: 256 thr / 4 waves =
// wq2 x wk2; k-tile 128, wave owns 64 k-cols (kfrag[2][4] regs) x its 32-q
// half; 8 LDS reads -> 16 MFMA per step. K staging area is reused as the
// second Q/V buffer after kfrag extraction -> LDS 32KB -> 4 blocks/CU,
// grid 1024 = exactly 1024 slots (clean). Partials combined via LDS at end.
__global__ __launch_bounds__(256, 4) void attn_pass2(const float* __restrict__ Q,
                                                     const float* __restrict__ K,
                                                     const float* __restrict__ V,
                                                     const float* __restrict__ invl,
                                                     float* __restrict__ out) {
    __shared__ __align__(16) char lds[32768];
    // K[128][64] staged at [0,16K), then that area becomes Q1/V1:
    //   buf0: Q @16K, V @24K ; buf1: Q @0K, V @8K

    int bid = blockIdx.x;
    int sb = (bid & 7) * 128 + (bid >> 3);   // bijective XCD swizzle (1024 = 8*128)
    int bh = sb >> 4;
    int k0 = (sb & 15) << 7;                 // 16 k-tiles of 128 per head
    const float* Qh = Q + (size_t)bh * L_SEQ * D_HEAD;
    const float* Kh = K + (size_t)bh * L_SEQ * D_HEAD + (size_t)k0 * D_HEAD;
    const float* Vh = V + (size_t)bh * D_HEAD * L_SEQ;
    const float* il = invl + (size_t)bh * L_SEQ;
    float* Oh = out + (size_t)bh * D_HEAD * L_SEQ;

    int t = threadIdx.x, lane = t & 63, w = t >> 6;
    int wq = w >> 1, wk = w & 1;
    int hl = lane >> 5, l31 = lane & 31;
    int r0 = t >> 4;          // staging row 0..15
    int c4 = (t & 15) << 2;   // staging col group

    // prologue A: stage K[128][64] -> [0,16K), kfrags -> regs
    {
        float4 one = make_float4(1.f, 1.f, 1.f, 1.f);
#pragma unroll
        for (int i = 0; i < 8; ++i) {
            float4 v = *reinterpret_cast<const float4*>(Kh + (size_t)(r0 + i * 16) * D_HEAD + c4);
            pack_write(lds, r0 + i * 16, c4, v, one);
        }
    }
    __syncthreads();
    bf16x8 kfrag[2][4];
#pragma unroll
    for (int kb = 0; kb < 2; ++kb)
#pragma unroll
        for (int m = 0; m < 4; ++m)
            kfrag[kb][m] = read_frag(lds, wk * 64 + kb * 32 + l31, m * 16 + hl * 8);

    // prologue B: stage Q0 / V0 (V scaled by invl; V cols = q)
    {
        float4 qs = make_float4(QSCALE, QSCALE, QSCALE, QSCALE);
        float4 iv = *reinterpret_cast<const float4*>(il + c4);
#pragma unroll
        for (int i = 0; i < 4; ++i) {
            float4 qv = *reinterpret_cast<const float4*>(Qh + (size_t)(r0 + i * 16) * D_HEAD + c4);
            float4 vv = *reinterpret_cast<const float4*>(Vh + (size_t)(r0 + i * 16) * L_SEQ + c4);
            pack_write(lds + 16384, r0 + i * 16, c4, qv, qs);
            pack_write(lds + 24576, r0 + i * 16, c4, vv, iv);
        }
    }
    __syncthreads();   // also guarantees every wave's kfrag reads are done

    f32x16 acc[2][2];   // [db][kb] partial over this wave's q-half
#pragma unroll
    for (int db = 0; db < 2; ++db)
#pragma unroll
        for (int kb = 0; kb < 2; ++kb)
#pragma unroll
            for (int r = 0; r < 16; ++r) acc[db][kb][r] = 0.f;

    for (int q0 = 0; q0 < L_SEQ; q0 += 64) {
        int c = (q0 >> 6) & 1;
        const char* qcur = lds + (c ? 0 : 16384);
        const char* vcur = lds + (c ? 8192 : 24576);
        char* qnext = lds + (c ? 16384 : 0);
        char* vnext = lds + (c ? 24576 : 8192);

        // issue next-tile loads (wrapped on last iter)
        int nq0 = (q0 + 64) & (L_SEQ - 1);
        float4 qreg[4], vreg[4];
#pragma unroll
        for (int i = 0; i < 4; ++i) {
            qreg[i] = *reinterpret_cast<const float4*>(Qh + (size_t)(nq0 + r0 + i * 16) * D_HEAD + c4);
            vreg[i] = *reinterpret_cast<const float4*>(Vh + (size_t)(r0 + i * 16) * L_SEQ + nq0 + c4);
        }
        float4 ivn = *reinterpret_cast<const float4*>(il + nq0 + c4);

        // S = Q.K^T for this wave's 32-q half x 64 k-cols (4 reads -> 8 MFMA)
        f32x16 s[2];
#pragma unroll
        for (int kb = 0; kb < 2; ++kb)
#pragma unroll
            for (int r = 0; r < 16; ++r) s[kb][r] = 0.f;

        __builtin_amdgcn_s_setprio(1);
#pragma unroll
        for (int m = 0; m < 4; ++m) {
            bf16x8 afr = read_frag(qcur, wq * 32 + l31, m * 16 + hl * 8);
            s[0] = __builtin_amdgcn_mfma_f32_32x32x16_bf16(afr, kfrag[0][m], s[0], 0, 0, 0);
            s[1] = __builtin_amdgcn_mfma_f32_32x32x16_bf16(afr, kfrag[1][m], s[1], 0, 0, 0);
        }
        __builtin_amdgcn_s_setprio(0);

        // P = exp2(s) -> bf16 frag words in-register
        bf16x8 pfrag[2][2];
#pragma unroll
        for (int kb = 0; kb < 2; ++kb) {
            unsigned wA[4], wB[4];
#pragma unroll
            for (int g = 0; g < 4; ++g) {
                wA[g] = cvt_pk_bf16(__builtin_amdgcn_exp2f(s[kb][4 * g + 0]),
                                    __builtin_amdgcn_exp2f(s[kb][4 * g + 1]));
                wB[g] = cvt_pk_bf16(__builtin_amdgcn_exp2f(s[kb][4 * g + 2]),
                                    __builtin_amdgcn_exp2f(s[kb][4 * g + 3]));
            }
#pragma unroll
            for (int mm = 0; mm < 2; ++mm) {
                unsigned a0 = wA[2 * mm], b0 = wA[2 * mm + 1];
                unsigned a1 = wB[2 * mm], b1 = wB[2 * mm + 1];
                asm volatile("v_permlane32_swap_b32 %0, %1" : "+v"(a0), "+v"(b0));
                asm volatile("v_permlane32_swap_b32 %0, %1" : "+v"(a1), "+v"(b1));
                union { unsigned u[4]; bf16x8 v; } pk;
                pk.u[0] = a0;
                pk.u[1] = a1;
                pk.u[2] = b0;
                pk.u[3] = b1;
                pfrag[kb][mm] = pk.v;
            }
        }

        // PV: 4 V reads feed 8 MFMA (4 independent acc chains)
        __builtin_amdgcn_s_setprio(1);
#pragma unroll
        for (int mm = 0; mm < 2; ++mm)
#pragma unroll
            for (int db = 0; db < 2; ++db) {
                bf16x8 vfr = read_frag(vcur, db * 32 + l31, wq * 32 + mm * 16 + hl * 8);
#pragma unroll
                for (int kb = 0; kb < 2; ++kb)
                    acc[db][kb] = __builtin_amdgcn_mfma_f32_32x32x16_bf16(
                        vfr, pfrag[kb][mm], acc[db][kb], 0, 0, 0);
            }
        __builtin_amdgcn_s_setprio(0);

        // write next Q/V, flip
        {
            float4 qs = make_float4(QSCALE, QSCALE, QSCALE, QSCALE);
#pragma unroll
            for (int i = 0; i < 4; ++i) {
                pack_write(qnext, r0 + i * 16, c4, qreg[i], qs);
                pack_write(vnext, r0 + i * 16, c4, vreg[i], ivn);
            }
        }
        __syncthreads();   // single barrier per 64-q step
    }

    // epilogue: combine wq partials via LDS, wq=0 stores
    __syncthreads();
    float* exf = reinterpret_cast<float*>(lds);   // 32 KB exchange
    if (wq == 1) {
#pragma unroll
        for (int db = 0; db < 2; ++db)
#pragma unroll
            for (int kb = 0; kb < 2; ++kb)
#pragma unroll
                for (int r = 0; r < 16; ++r)
                    exf[(((wk * 2 + db) * 2 + kb) * 16 + r) * 64 + lane] = acc[db][kb][r];
    }
    __syncthreads();
    if (wq == 0) {
#pragma unroll
        for (int db = 0; db < 2; ++db)
#pragma unroll
            for (int kb = 0; kb < 2; ++kb)
#pragma unroll
                for (int r = 0; r < 16; ++r) {
                    float v = acc[db][kb][r] +
                              exf[(((wk * 2 + db) * 2 + kb) * 16 + r) * 64 + lane];
                    int d = db * 32 + (r & 3) + 8 * (r >> 2) + 4 * hl;
                    int k = k0 + wk * 64 + kb * 32 + l31;
                    Oh[(size_t)d * L_SEQ + k] = v;
                }
    }
}

extern "C" void kernel_launch(void* const* d_in, const int* in_sizes, int n_in,
                              void* d_out, int out_size, void* d_ws, size_t ws_size,
                              hipStream_t stream) {
    const float* Q = (const float*)d_in[0];
    const float* K = (const float*)d_in[1];
    const float* V = (const float*)d_in[2];
    float* invl = (float*)d_ws;          // NHEADS * L_SEQ floats = 512 KB
    float* out = (float*)d_out;

    attn_pass1<<<dim3(NHEADS * (L_SEQ / 128)), dim3(256), 0, stream>>>(Q, K, invl);
    attn_pass2<<<dim3(NHEADS * (L_SEQ / 128)), dim3(256), 0, stream>>>(Q, K, V, invl, out);
}

// Round 13
// 270.338 us; speedup vs baseline: 1.2935x; 1.2935x over previous
//
#include <hip/hip_runtime.h>
#include <hip/hip_bf16.h>

#define L_SEQ 2048
#define D_HEAD 64
#define NHEADS 64   // B*H
#define QSCALE (0.125f * 1.44269504088896340736f)  // 1/sqrt(64) * log2(e)

typedef __attribute__((ext_vector_type(8))) __bf16 bf16x8;
typedef __attribute__((ext_vector_type(16))) float f32x16;

// [rows][64] bf16 tile (128B rows), XOR-swizzled (G4).
__device__ __forceinline__ int swz(int row, int col) {
    int off = (row << 7) | (col << 1);
    return off ^ ((row & 7) << 4);
}
__device__ __forceinline__ bf16x8 read_frag(const char* lds, int row, int col) {
    return *reinterpret_cast<const bf16x8*>(lds + swz(row, col));
}
__device__ __forceinline__ void pack_write(char* lds, int row, int c4, float4 v,
                                           float4 sc) {
    union { __bf16 h[4]; unsigned long long u; } pk;
    pk.h[0] = (__bf16)(v.x * sc.x);
    pk.h[1] = (__bf16)(v.y * sc.y);
    pk.h[2] = (__bf16)(v.z * sc.z);
    pk.h[3] = (__bf16)(v.w * sc.w);
    *reinterpret_cast<unsigned long long*>(lds + swz(row, c4)) = pk.u;
}

__device__ __forceinline__ unsigned cvt_pk_bf16(float lo, float hi) {
    unsigned r;
    asm("v_cvt_pk_bf16_f32 %0, %1, %2" : "=v"(r) : "v"(lo), "v"(hi));
    return r;
}

// -------- Pass 1: invl[bh][q] = 1 / sum_k exp2(QSCALE*(Q.K)) ----------------
// Round-8/10 version (measured ~40-48 us): q-tile 128, 4 waves = wq2 x wk2,
// k-step 64 double-buffered, one barrier/step. Grid 1024 @ 4/CU = clean.
__global__ __launch_bounds__(256, 4) void attn_pass1(const float* __restrict__ Q,
                                                     const float* __restrict__ K,
                                                     float* __restrict__ invl) {
    __shared__ __align__(16) char lds[16384];   // Q stage, then 2 x 8KB K dbuf
    __shared__ float red[2][128];

    int bid = blockIdx.x;
    int sb = (bid & 7) * 128 + (bid >> 3);   // bijective XCD swizzle (1024 = 8*128)
    int bh = sb >> 4;
    int q0 = (sb & 15) << 7;
    const float* Qh = Q + (size_t)bh * L_SEQ * D_HEAD + (size_t)q0 * D_HEAD;
    const float* Kh = K + (size_t)bh * L_SEQ * D_HEAD;

    int t = threadIdx.x, lane = t & 63, w = t >> 6;
    int wq = w >> 1, wk = w & 1;
    int hl = lane >> 5, l31 = lane & 31;
    int r0 = t >> 4;          // 0..15
    int c4 = (t & 15) << 2;

    // stage Q[128][64] (rows 0..127 across the 16KB region)
    {
        float4 qs = make_float4(QSCALE, QSCALE, QSCALE, QSCALE);
#pragma unroll
        for (int i = 0; i < 8; ++i) {
            float4 v = *reinterpret_cast<const float4*>(Qh + (size_t)(r0 + i * 16) * D_HEAD + c4);
            pack_write(lds, r0 + i * 16, c4, v, qs);
        }
    }
    __syncthreads();
    bf16x8 qfrag[2][4];
#pragma unroll
    for (int qb = 0; qb < 2; ++qb)
#pragma unroll
        for (int m = 0; m < 4; ++m)
            qfrag[qb][m] = read_frag(lds, wq * 64 + qb * 32 + l31, m * 16 + hl * 8);
    __syncthreads();
    // stage K tile 0 into buf0
    {
        float4 one = make_float4(1.f, 1.f, 1.f, 1.f);
#pragma unroll
        for (int i = 0; i < 4; ++i) {
            float4 v = *reinterpret_cast<const float4*>(Kh + (size_t)(r0 + i * 16) * D_HEAD + c4);
            pack_write(lds, r0 + i * 16, c4, v, one);
        }
    }
    __syncthreads();

    float lsum[2][16];
#pragma unroll
    for (int qb = 0; qb < 2; ++qb)
#pragma unroll
        for (int r = 0; r < 16; ++r) lsum[qb][r] = 0.f;

    for (int k0 = 0; k0 < L_SEQ; k0 += 64) {
        int c = (k0 >> 6) & 1;
        const char* kcur = lds + (c ? 8192 : 0);
        char* knext = lds + (c ? 0 : 8192);

        int nk0 = (k0 + 64) & (L_SEQ - 1);
        float4 kreg[4];
#pragma unroll
        for (int i = 0; i < 4; ++i)
            kreg[i] = *reinterpret_cast<const float4*>(Kh + (size_t)(nk0 + r0 + i * 16) * D_HEAD + c4);

        bf16x8 kfr[4];
#pragma unroll
        for (int m = 0; m < 4; ++m)
            kfr[m] = read_frag(kcur, wk * 32 + l31, m * 16 + hl * 8);

        __builtin_amdgcn_s_setprio(1);
#pragma unroll
        for (int qb = 0; qb < 2; ++qb) {
            f32x16 s;
#pragma unroll
            for (int r = 0; r < 16; ++r) s[r] = 0.f;
#pragma unroll
            for (int m = 0; m < 4; ++m)
                s = __builtin_amdgcn_mfma_f32_32x32x16_bf16(qfrag[qb][m], kfr[m], s, 0, 0, 0);
#pragma unroll
            for (int r = 0; r < 16; ++r)
                lsum[qb][r] += __builtin_amdgcn_exp2f(s[r]);
        }
        __builtin_amdgcn_s_setprio(0);

        {
            float4 one = make_float4(1.f, 1.f, 1.f, 1.f);
#pragma unroll
            for (int i = 0; i < 4; ++i)
                pack_write(knext, r0 + i * 16, c4, kreg[i], one);
        }
        __syncthreads();   // single barrier per step (double-buffered)
    }

    // reduce over this wave's 32 k-lanes
#pragma unroll
    for (int qb = 0; qb < 2; ++qb)
#pragma unroll
        for (int r = 0; r < 16; ++r) {
            float v = lsum[qb][r];
            v += __shfl_xor(v, 1);
            v += __shfl_xor(v, 2);
            v += __shfl_xor(v, 4);
            v += __shfl_xor(v, 8);
            v += __shfl_xor(v, 16);
            lsum[qb][r] = v;
        }
    if (l31 == 0) {
#pragma unroll
        for (int qb = 0; qb < 2; ++qb)
#pragma unroll
            for (int r = 0; r < 16; ++r)
                red[wk][wq * 64 + qb * 32 + (r & 3) + 8 * (r >> 2) + 4 * hl] = lsum[qb][r];
    }
    __syncthreads();
    if (t < 128) {
        float ssum = red[0][t] + red[1][t];
        invl[(size_t)bh * L_SEQ + q0 + t] = 1.0f / ssum;
    }
}

// -------- Pass 2: Out[d, k-tile] = sum_q (V[d,q]*invl[q]) * exp2(s[q,k]) ----
// 512 thr / 8 waves = wq2 x wk4; k-tile 256 (8 blocks/head -> L2 reuse OK).
// Wave owns 64 k-cols (kfrag[2][4] regs) x its 32-q half of each 64-q step:
// 8 LDS frag reads -> 16 MFMA (1:2). K staged in all 32KB LDS -> regs, area
// reused as Q/V dbuf -> 2 blocks/CU x 8 waves = 4 waves/SIMD, grid 512 clean.
// wq-partials combined via 2-round (per-kb) 32KB LDS exchange epilogue.
__global__ __launch_bounds__(512, 4) void attn_pass2(const float* __restrict__ Q,
                                                     const float* __restrict__ K,
                                                     const float* __restrict__ V,
                                                     const float* __restrict__ invl,
                                                     float* __restrict__ out) {
    __shared__ __align__(16) char lds[32768];
    // phase 1: K[256][64] staging; phase 2: Q0 @0, V0 @8K, Q1 @16K, V1 @24K

    int bid = blockIdx.x;
    int sb = (bid & 7) * 64 + (bid >> 3);    // bijective XCD swizzle (512 = 8*64)
    int bh = sb >> 3;
    int k0 = (sb & 7) << 8;
    const float* Qh = Q + (size_t)bh * L_SEQ * D_HEAD;
    const float* Kh = K + (size_t)bh * L_SEQ * D_HEAD + (size_t)k0 * D_HEAD;
    const float* Vh = V + (size_t)bh * D_HEAD * L_SEQ;
    const float* il = invl + (size_t)bh * L_SEQ;
    float* Oh = out + (size_t)bh * D_HEAD * L_SEQ;

    int t = threadIdx.x, lane = t & 63, w = t >> 6;    // w 0..7
    int wq = w >> 2, wk = w & 3;
    int hl = lane >> 5, l31 = lane & 31;
    int r0 = t >> 4;          // 0..31 (staging row)
    int c4 = (t & 15) << 2;   // staging col group

    // prologue A: stage K[256][64] across all 32KB, kfrags -> regs
    {
        float4 one = make_float4(1.f, 1.f, 1.f, 1.f);
#pragma unroll
        for (int i = 0; i < 8; ++i) {
            float4 v = *reinterpret_cast<const float4*>(Kh + (size_t)(r0 + i * 32) * D_HEAD + c4);
            pack_write(lds, r0 + i * 32, c4, v, one);
        }
    }
    __syncthreads();
    bf16x8 kfrag[2][4];
#pragma unroll
    for (int kb = 0; kb < 2; ++kb)
#pragma unroll
        for (int m = 0; m < 4; ++m)
            kfrag[kb][m] = read_frag(lds, wk * 64 + kb * 32 + l31, m * 16 + hl * 8);
    __syncthreads();   // all kfrag reads done before K area is overwritten

    // prologue B: stage Q0 / V0 (V scaled by invl; V cols = q)
    {
        float4 qs = make_float4(QSCALE, QSCALE, QSCALE, QSCALE);
        float4 iv = *reinterpret_cast<const float4*>(il + c4);
#pragma unroll
        for (int i = 0; i < 2; ++i) {
            float4 qv = *reinterpret_cast<const float4*>(Qh + (size_t)(r0 + i * 32) * D_HEAD + c4);
            float4 vv = *reinterpret_cast<const float4*>(Vh + (size_t)(r0 + i * 32) * L_SEQ + c4);
            pack_write(lds, r0 + i * 32, c4, qv, qs);
            pack_write(lds + 8192, r0 + i * 32, c4, vv, iv);
        }
    }
    __syncthreads();

    f32x16 acc[2][2];   // [db][kb] partial over this wave's q-half
#pragma unroll
    for (int db = 0; db < 2; ++db)
#pragma unroll
        for (int kb = 0; kb < 2; ++kb)
#pragma unroll
            for (int r = 0; r < 16; ++r) acc[db][kb][r] = 0.f;

    for (int q0 = 0; q0 < L_SEQ; q0 += 64) {
        int c = (q0 >> 6) & 1;
        const char* qcur = lds + (c ? 16384 : 0);
        const char* vcur = lds + (c ? 24576 : 8192);
        char* qnext = lds + (c ? 0 : 16384);
        char* vnext = lds + (c ? 8192 : 24576);

        // issue next-tile loads (wrapped on last iter)
        int nq0 = (q0 + 64) & (L_SEQ - 1);
        float4 qreg[2], vreg[2];
#pragma unroll
        for (int i = 0; i < 2; ++i) {
            qreg[i] = *reinterpret_cast<const float4*>(Qh + (size_t)(nq0 + r0 + i * 32) * D_HEAD + c4);
            vreg[i] = *reinterpret_cast<const float4*>(Vh + (size_t)(r0 + i * 32) * L_SEQ + nq0 + c4);
        }
        float4 ivn = *reinterpret_cast<const float4*>(il + nq0 + c4);

        // S = Q.K^T for this wave's 32-q half x 64 k-cols (4 reads -> 8 MFMA)
        f32x16 s[2];
#pragma unroll
        for (int kb = 0; kb < 2; ++kb)
#pragma unroll
            for (int r = 0; r < 16; ++r) s[kb][r] = 0.f;

        __builtin_amdgcn_s_setprio(1);
#pragma unroll
        for (int m = 0; m < 4; ++m) {
            bf16x8 afr = read_frag(qcur, wq * 32 + l31, m * 16 + hl * 8);
            s[0] = __builtin_amdgcn_mfma_f32_32x32x16_bf16(afr, kfrag[0][m], s[0], 0, 0, 0);
            s[1] = __builtin_amdgcn_mfma_f32_32x32x16_bf16(afr, kfrag[1][m], s[1], 0, 0, 0);
        }
        __builtin_amdgcn_s_setprio(0);

        // P = exp2(s) -> bf16 frag words in-register
        bf16x8 pfrag[2][2];
#pragma unroll
        for (int kb = 0; kb < 2; ++kb) {
            unsigned wA[4], wB[4];
#pragma unroll
            for (int g = 0; g < 4; ++g) {
                wA[g] = cvt_pk_bf16(__builtin_amdgcn_exp2f(s[kb][4 * g + 0]),
                                    __builtin_amdgcn_exp2f(s[kb][4 * g + 1]));
                wB[g] = cvt_pk_bf16(__builtin_amdgcn_exp2f(s[kb][4 * g + 2]),
                                    __builtin_amdgcn_exp2f(s[kb][4 * g + 3]));
            }
#pragma unroll
            for (int mm = 0; mm < 2; ++mm) {
                unsigned a0 = wA[2 * mm], b0 = wA[2 * mm + 1];
                unsigned a1 = wB[2 * mm], b1 = wB[2 * mm + 1];
                asm volatile("v_permlane32_swap_b32 %0, %1" : "+v"(a0), "+v"(b0));
                asm volatile("v_permlane32_swap_b32 %0, %1" : "+v"(a1), "+v"(b1));
                union { unsigned u[4]; bf16x8 v; } pk;
                pk.u[0] = a0;
                pk.u[1] = a1;
                pk.u[2] = b0;
                pk.u[3] = b1;
                pfrag[kb][mm] = pk.v;
            }
        }

        // PV: 4 V reads feed 8 MFMA (4 independent acc chains)
        __builtin_amdgcn_s_setprio(1);
#pragma unroll
        for (int mm = 0; mm < 2; ++mm)
#pragma unroll
            for (int db = 0; db < 2; ++db) {
                bf16x8 vfr = read_frag(vcur, db * 32 + l31, wq * 32 + mm * 16 + hl * 8);
#pragma unroll
                for (int kb = 0; kb < 2; ++kb)
                    acc[db][kb] = __builtin_amdgcn_mfma_f32_32x32x16_bf16(
                        vfr, pfrag[kb][mm], acc[db][kb], 0, 0, 0);
            }
        __builtin_amdgcn_s_setprio(0);

        // write next Q/V, flip
        {
            float4 qs = make_float4(QSCALE, QSCALE, QSCALE, QSCALE);
#pragma unroll
            for (int i = 0; i < 2; ++i) {
                pack_write(qnext, r0 + i * 32, c4, qreg[i], qs);
                pack_write(vnext, r0 + i * 32, c4, vreg[i], ivn);
            }
        }
        __syncthreads();   // single barrier per 64-q step
    }

    // epilogue: combine wq partials via LDS (one 32KB round per kb)
    float* exf = reinterpret_cast<float*>(lds);
#pragma unroll
    for (int kb = 0; kb < 2; ++kb) {
        __syncthreads();
        if (wq == 1) {
#pragma unroll
            for (int db = 0; db < 2; ++db)
#pragma unroll
                for (int r = 0; r < 16; ++r)
                    exf[((wk * 2 + db) * 16 + r) * 64 + lane] = acc[db][kb][r];
        }
        __syncthreads();
        if (wq == 0) {
#pragma unroll
            for (int db = 0; db < 2; ++db)
#pragma unroll
                for (int r = 0; r < 16; ++r) {
                    float v = acc[db][kb][r] +
                              exf[((wk * 2 + db) * 16 + r) * 64 + lane];
                    int d = db * 32 + (r & 3) + 8 * (r >> 2) + 4 * hl;
                    int k = k0 + wk * 64 + kb * 32 + l31;
                    Oh[(size_t)d * L_SEQ + k] = v;
                }
        }
    }
}

extern "C" void kernel_launch(void* const* d_in, const int* in_sizes, int n_in,
                              void* d_out, int out_size, void* d_ws, size_t ws_size,
                              hipStream_t stream) {
    const float* Q = (const float*)d_in[0];
    const float* K = (const float*)d_in[1];
    const float* V = (const float*)d_in[2];
    float* invl = (float*)d_ws;          // NHEADS * L_SEQ floats = 512 KB
    float* out = (float*)d_out;

    attn_pass1<<<dim3(NHEADS * (L_SEQ / 128)), dim3(256), 0, stream>>>(Q, K, invl);
    attn_pass2<<<dim3(NHEADS * (L_SEQ / 256)), dim3(512), 0, stream>>>(Q, K, V, invl, out);
}